// Round 22
// baseline (193.758 us; speedup 1.0000x reference)
//
#include <hip/hip_runtime.h>
#include <stdint.h>

#define B_   4
#define S_   2048
#define H_   16
#define DK_  64
#define DM_  1024
#define M_   (B_ * S_)   // 8192

typedef __attribute__((ext_vector_type(4)))  float f32x4;
typedef __attribute__((ext_vector_type(16))) float f32x16;
typedef __attribute__((ext_vector_type(8)))  short s16x8;

#define SCQ 0.18033688011112042f   // (1/sqrt(64)) * log2(e), folded into Q

__device__ __forceinline__ uint16_t f2bf(float f) {
    union { float f; uint32_t u; } v; v.f = f;
    uint32_t u = v.u;
    uint32_t r = (u + 0x7FFFu + ((u >> 16) & 1u)) >> 16;  // RNE
    return (uint16_t)r;
}
__device__ __forceinline__ float bf2f(uint16_t h) {
    union { uint32_t u; float f; } v; v.u = ((uint32_t)h) << 16;
    return v.f;
}
__device__ __forceinline__ uint32_t cvt_pk_bf16(float lo, float hi) {
    uint32_t r;
    asm("v_cvt_pk_bf16_f32 %0, %1, %2" : "=v"(r) : "v"(lo), "v"(hi));
    return r;
}

// async global->LDS, 16B per lane; lds base must be wave-uniform
__device__ __forceinline__ void gload_lds16(const uint16_t* g, uint16_t* l) {
    __builtin_amdgcn_global_load_lds(
        (const __attribute__((address_space(1))) void*)g,
        (__attribute__((address_space(3))) void*)l, 16, 0, 0);
}

// ---------------- fp32 -> bf16 convert, ALL inputs in one launch ----------------
__global__ __launch_bounds__(256) void cvt_all(const float* __restrict__ x,
                                               const float* __restrict__ w0,
                                               const float* __restrict__ w1,
                                               const float* __restrict__ w2,
                                               const float* __restrict__ w3,
                                               uint16_t* __restrict__ xo,
                                               uint16_t* __restrict__ o0,
                                               uint16_t* __restrict__ o1,
                                               uint16_t* __restrict__ o2,
                                               uint16_t* __restrict__ o3) {
    const size_t NX = (size_t)M_ * DM_;
    const size_t NW = (size_t)DM_ * DM_;
    size_t i = ((size_t)blockIdx.x * 256 + threadIdx.x) * 4;
    const float* in; uint16_t* out; size_t off;
    if (i < NX) { in = x; out = xo; off = i; }
    else {
        size_t j = i - NX;
        int sel = (int)(j >> 20);
        off = j & (NW - 1);
        in  = sel == 0 ? w0 : sel == 1 ? w1 : sel == 2 ? w2 : w3;
        out = sel == 0 ? o0 : sel == 1 ? o1 : sel == 2 ? o2 : o3;
    }
    float4 v = *reinterpret_cast<const float4*>(in + off);
    ushort4 o;
    o.x = f2bf(v.x); o.y = f2bf(v.y); o.z = f2bf(v.z); o.w = f2bf(v.w);
    *reinterpret_cast<ushort4*>(out + off) = o;
}

// ---------------- fused QKV projection, dbuf, 32x32x16 MFMA ----------------
__global__ __launch_bounds__(256, 4) void gemm_qkv(const uint16_t* __restrict__ xb,
                                                   const uint16_t* __restrict__ wq,
                                                   const uint16_t* __restrict__ wk,
                                                   const uint16_t* __restrict__ wv,
                                                   uint16_t* __restrict__ qout,
                                                   uint16_t* __restrict__ kout,
                                                   uint16_t* __restrict__ vout) {
    __shared__ uint16_t Al[2][128 * 32];
    __shared__ uint16_t Bl[2][128 * 32];
    const int K = DM_;
    const int lane = threadIdx.x & 63;
    const int w    = threadIdx.x >> 6;
    const int wr   = w >> 1, wc = w & 1;
    const int sel  = blockIdx.x >> 3;
    const int np   = blockIdx.x & 7;
    const int y    = blockIdx.y;
    const int ql   = lane & 31;
    const int hi   = lane >> 5;

    const uint16_t* Aptr; const uint16_t* Bptr;
    int m0, n0;
    if (sel == 2) { Aptr = wv; Bptr = xb; m0 = np * 128; n0 = y * 128; }
    else          { Aptr = xb; Bptr = sel ? wk : wq; m0 = y * 128; n0 = np * 128; }

    const int srow = w * 32 + (lane >> 2);
    const int scol = (((lane & 3) ^ ((lane >> 3) & 3))) * 8;   // key=(row>>1)&3
    const uint16_t* Ag = Aptr + (size_t)(m0 + srow) * K + scol;
    const uint16_t* Bg = Bptr + (size_t)(n0 + srow) * K + scol;
    const int loff = w * 32 * 32;   // wave-uniform LDS base (elements)
    const int qsw  = (ql >> 1) & 3; // read-side XOR key ((ROW>>1)&3)

    f32x16 acc[2][2] = {};
    // prologue: stage K-step 0 into buffer 0
#pragma unroll
    for (int i = 0; i < 2; ++i) {
        gload_lds16(Ag + (size_t)i * 16 * K, &Al[0][loff + i * 16 * 32]);
        gload_lds16(Bg + (size_t)i * 16 * K, &Bl[0][loff + i * 16 * 32]);
    }

    int cur = 0;
    for (int k0 = 0; k0 < K; k0 += 32) {
        __syncthreads();   // drains vmcnt: buf[cur] landed; buf[cur^1] reads done
        if (k0 + 32 < K) {
            const int nb = cur ^ 1, k2 = k0 + 32;
#pragma unroll
            for (int i = 0; i < 2; ++i) {
                gload_lds16(Ag + (size_t)i * 16 * K + k2, &Al[nb][loff + i * 16 * 32]);
                gload_lds16(Bg + (size_t)i * 16 * K + k2, &Bl[nb][loff + i * 16 * 32]);
            }
        }
        s16x8 af[2][2], bfr[2][2];
#pragma unroll
        for (int am = 0; am < 2; ++am)
#pragma unroll
            for (int ks = 0; ks < 2; ++ks)
                af[am][ks] = *reinterpret_cast<const s16x8*>(
                    &Al[cur][(wr * 64 + am * 32 + ql) * 32 + (((ks * 2 + hi) ^ qsw) * 8)]);
#pragma unroll
        for (int bn = 0; bn < 2; ++bn)
#pragma unroll
            for (int ks = 0; ks < 2; ++ks)
                bfr[bn][ks] = *reinterpret_cast<const s16x8*>(
                    &Bl[cur][(wc * 64 + bn * 32 + ql) * 32 + (((ks * 2 + hi) ^ qsw) * 8)]);
#pragma unroll
        for (int am = 0; am < 2; ++am)
#pragma unroll
            for (int bn = 0; bn < 2; ++bn) {
                acc[am][bn] = __builtin_amdgcn_mfma_f32_32x32x16_bf16(af[am][0], bfr[bn][0],
                                                                      acc[am][bn], 0, 0, 0);
                acc[am][bn] = __builtin_amdgcn_mfma_f32_32x32x16_bf16(af[am][1], bfr[bn][1],
                                                                      acc[am][bn], 0, 0, 0);
            }
        cur ^= 1;
    }

#pragma unroll
    for (int am = 0; am < 2; ++am)
#pragma unroll
        for (int bn = 0; bn < 2; ++bn)
#pragma unroll
            for (int r = 0; r < 16; ++r) {
                const int cr = (r & 3) + 8 * (r >> 2);
                int row = m0 + wr * 64 + am * 32 + 4 * hi + cr;
                int col = n0 + wc * 64 + bn * 32 + ql;
                float v = acc[am][bn][r];
                if (sel == 2) {   // row over DM (h,dk), col over M (b,s)
                    int h = row >> 6,  dk = row & 63;
                    int b = col >> 11, s = col & (S_ - 1);
                    vout[(((size_t)(b * H_ + h)) * DK_ + dk) * S_ + s] = f2bf(v);
                } else {
                    int b = row >> 11, s = row & (S_ - 1);
                    int h = col >> 6,  dk = col & 63;
                    uint16_t bv = f2bf(sel ? v : v * SCQ);
                    (sel ? kout : qout)[(((size_t)(b * H_ + h)) * S_ + s) * DK_ + dk] = bv;
                }
            }
}

// ---------------- out-projection GEMM, dbuf, 32x32x16: C fp32 = attn * wo^T ----
__global__ __launch_bounds__(256, 4) void gemm_out(const uint16_t* __restrict__ A,
                                                   const uint16_t* __restrict__ Bm,
                                                   float* __restrict__ Cout,
                                                   int M, int N, int K) {
    __shared__ uint16_t Al[2][128 * 32];
    __shared__ uint16_t Bl[2][128 * 32];
    const int lane = threadIdx.x & 63;
    const int w    = threadIdx.x >> 6;
    const int wr   = w >> 1, wc = w & 1;
    const int m0   = blockIdx.x * 128;
    const int n0   = blockIdx.y * 128;
    const int ql   = lane & 31;
    const int hi   = lane >> 5;

    const int srow = w * 32 + (lane >> 2);
    const int scol = (((lane & 3) ^ ((lane >> 3) & 3))) * 8;
    const uint16_t* Ag = A  + (size_t)(m0 + srow) * K + scol;
    const uint16_t* Bg = Bm + (size_t)(n0 + srow) * K + scol;
    const int loff = w * 32 * 32;
    const int qsw  = (ql >> 1) & 3;

    f32x16 acc[2][2] = {};
#pragma unroll
    for (int i = 0; i < 2; ++i) {
        gload_lds16(Ag + (size_t)i * 16 * K, &Al[0][loff + i * 16 * 32]);
        gload_lds16(Bg + (size_t)i * 16 * K, &Bl[0][loff + i * 16 * 32]);
    }

    int cur = 0;
    for (int k0 = 0; k0 < K; k0 += 32) {
        __syncthreads();
        if (k0 + 32 < K) {
            const int nb = cur ^ 1, k2 = k0 + 32;
#pragma unroll
            for (int i = 0; i < 2; ++i) {
                gload_lds16(Ag + (size_t)i * 16 * K + k2, &Al[nb][loff + i * 16 * 32]);
                gload_lds16(Bg + (size_t)i * 16 * K + k2, &Bl[nb][loff + i * 16 * 32]);
            }
        }
        s16x8 af[2][2], bfr[2][2];
#pragma unroll
        for (int am = 0; am < 2; ++am)
#pragma unroll
            for (int ks = 0; ks < 2; ++ks)
                af[am][ks] = *reinterpret_cast<const s16x8*>(
                    &Al[cur][(wr * 64 + am * 32 + ql) * 32 + (((ks * 2 + hi) ^ qsw) * 8)]);
#pragma unroll
        for (int bn = 0; bn < 2; ++bn)
#pragma unroll
            for (int ks = 0; ks < 2; ++ks)
                bfr[bn][ks] = *reinterpret_cast<const s16x8*>(
                    &Bl[cur][(wc * 64 + bn * 32 + ql) * 32 + (((ks * 2 + hi) ^ qsw) * 8)]);
#pragma unroll
        for (int am = 0; am < 2; ++am)
#pragma unroll
            for (int bn = 0; bn < 2; ++bn) {
                acc[am][bn] = __builtin_amdgcn_mfma_f32_32x32x16_bf16(af[am][0], bfr[bn][0],
                                                                      acc[am][bn], 0, 0, 0);
                acc[am][bn] = __builtin_amdgcn_mfma_f32_32x32x16_bf16(af[am][1], bfr[bn][1],
                                                                      acc[am][bn], 0, 0, 0);
            }
        cur ^= 1;
    }

#pragma unroll
    for (int am = 0; am < 2; ++am)
#pragma unroll
        for (int bn = 0; bn < 2; ++bn)
#pragma unroll
            for (int r = 0; r < 16; ++r) {
                const int cr = (r & 3) + 8 * (r >> 2);
                int row = m0 + wr * 64 + am * 32 + 4 * hi + cr;
                int col = n0 + wc * 64 + bn * 32 + ql;
                Cout[(size_t)row * N + col] = acc[am][bn][r];
            }
}

// ---------------- RoPE, K only (Q roped inside flash prologue) ----------------
__global__ __launch_bounds__(256) void rope_kernel(uint16_t* __restrict__ a,
                                                   const int* __restrict__ pos,
                                                   int npairs) {
    int t = blockIdx.x * 256 + threadIdx.x;
    if (t >= npairs) return;
    int j = t & 31;
    int s = (t >> 5) & (S_ - 1);
    float p   = (float)pos[s];
    float inv = exp2f(-(float)j * (13.287712379549449f / 32.0f));
    float ang = p * inv;
    float sn = __sinf(ang);
    float c  = __cosf(ang);
    uint32_t pr = *reinterpret_cast<uint32_t*>(a + (size_t)2 * t);
    float x0 = bf2f((uint16_t)(pr & 0xFFFF));
    float x1 = bf2f((uint16_t)(pr >> 16));
    float r0 = x0 * c - x1 * sn;
    float r1 = x0 * sn + x1 * c;
    uint32_t ot = (uint32_t)f2bf(r0) | ((uint32_t)f2bf(r1) << 16);
    *reinterpret_cast<uint32_t*>(a + (size_t)2 * t) = ot;
}

// ---------------- causal flash attention, 32x32 MFMA, 64 q-rows/wave ----------
// Two 32-row fragment groups (A,B) per wave SHARE each K/V LDS fragment read:
// 32 MFMA per 16 ds_read_b128 (2:1 vs old 1:1) -- LDS-read BW was the binder.
// 2 k-tiles staged per barrier; 64KB LDS -> 2 blocks/CU. Q-RoPE in prologue.
// Grid 512: block = 256 q-rows; zig-zag supertile order pairs heavy+light blocks.
__global__ __launch_bounds__(256, 2) void flash_attn(const uint16_t* __restrict__ qg,
                                                     const uint16_t* __restrict__ kg,
                                                     const uint16_t* __restrict__ vtg,
                                                     const int* __restrict__ tpos,
                                                     uint16_t* __restrict__ attn) {
    __shared__ __align__(16) uint16_t Kl[2][2][4096];  // [buf][half][64key x 64dk]
    __shared__ __align__(16) uint16_t Vl[2][2][4096];  // [buf][half][64dk x 64key]
    const int lane = threadIdx.x & 63;
    const int w    = threadIdx.x >> 6;     // 0..3
    const int ql   = lane & 31;
    const int hi   = lane >> 5;
    const int id   = blockIdx.x;
    const int bh   = (id & 7) * 8 + ((id >> 3) & 7);   // 8 bh per XCD
    const int zig  = id >> 6;              // 0..7
    const int ss   = (zig < 4) ? (7 - zig) : (zig - 4);   // {7,6,5,4,0,1,2,3}
    const int b    = bh >> 4, hh = bh & 15;

    const uint16_t* kb_ = kg  + (size_t)bh * S_ * DK_;
    const uint16_t* vb_ = vtg + (size_t)bh * DK_ * S_;

    char* obb = (char*)&Kl[0][0][0] + w * 4096;   // per-wave 4KB, aliases Kl[0]
    const int swz = (ql & 7) << 4;

    const int q0 = ss * 256 + w * 64;      // wave owns rows q0..q0+63
    const int rowA  = q0 + ql;
    const int rowB  = q0 + 32 + ql;
    const int ntmax = 4 * ss + 4;          // block-uniform, even (pairs exactly)

    const int srow = lane >> 3;                       // 0..7
    const int scol = ((lane & 7) ^ srow) << 3;        // pre-swizzled source chunk

    // Q load + fused RoPE for both row groups
    const float FR = 13.287712379549449f / 32.0f;     // log2(10000)/32
    s16x8 qfA[4], qfB[4];
    {
        const uint16_t* qpA = qg + ((size_t)bh * S_ + rowA) * DK_ + hi * 8;
        const uint16_t* qpB = qg + ((size_t)bh * S_ + rowB) * DK_ + hi * 8;
        const float pA = (float)tpos[rowA];
        const float pB = (float)tpos[rowB];
#pragma unroll
        for (int kk = 0; kk < 4; ++kk) {
            s16x8 rawA = *reinterpret_cast<const s16x8*>(qpA + kk * 16);
            s16x8 rawB = *reinterpret_cast<const s16x8*>(qpB + kk * 16);
            union { uint32_t u[4]; s16x8 v; } pwA, pwB;
#pragma unroll
            for (int jj = 0; jj < 4; ++jj) {
                float inv = exp2f(-(float)(kk * 8 + hi * 4 + jj) * FR);
                float aA = pA * inv, aB = pB * inv;
                float snA = __sinf(aA), csA = __cosf(aA);
                float snB = __sinf(aB), csB = __cosf(aB);
                float a0 = bf2f((uint16_t)rawA[2 * jj]), a1 = bf2f((uint16_t)rawA[2 * jj + 1]);
                float b0 = bf2f((uint16_t)rawB[2 * jj]), b1 = bf2f((uint16_t)rawB[2 * jj + 1]);
                pwA.u[jj] = cvt_pk_bf16(a0 * csA - a1 * snA, a0 * snA + a1 * csA);
                pwB.u[jj] = cvt_pk_bf16(b0 * csB - b1 * snB, b0 * snB + b1 * csB);
            }
            qfA[kk] = pwA.v;
            qfB[kk] = pwB.v;
        }
    }

    f32x16 oA0 = {}, oA1 = {}, oB0 = {}, oB1 = {};
    float lA = 0.f, lB = 0.f;

    // one 64-key sub-tile; all barriers live outside (wave-uniform skip inside)
    auto do_tile = [&](int kt, const uint16_t* Kh, const uint16_t* Vh) {
        if (kt > q0 + 63) return;          // fully masked for all 64 rows

        s16x8 kf[8];
#pragma unroll
        for (int kb2 = 0; kb2 < 2; ++kb2)
#pragma unroll
            for (int kk = 0; kk < 4; ++kk)
                kf[kb2 * 4 + kk] = *reinterpret_cast<const s16x8*>(
                    &Kh[(kb2 * 32 + ql) * 64 + (((kk * 32 + hi * 16) ^ swz) >> 1)]);

        f32x16 sA0 = {}, sA1 = {}, sB0 = {}, sB1 = {};
        __builtin_amdgcn_s_setprio(1);
#pragma unroll
        for (int kk = 0; kk < 4; ++kk) {
            sA0 = __builtin_amdgcn_mfma_f32_32x32x16_bf16(kf[kk],     qfA[kk], sA0, 0, 0, 0);
            sA1 = __builtin_amdgcn_mfma_f32_32x32x16_bf16(kf[4 + kk], qfA[kk], sA1, 0, 0, 0);
            sB0 = __builtin_amdgcn_mfma_f32_32x32x16_bf16(kf[kk],     qfB[kk], sB0, 0, 0, 0);
            sB1 = __builtin_amdgcn_mfma_f32_32x32x16_bf16(kf[4 + kk], qfB[kk], sB1, 0, 0, 0);
        }
        __builtin_amdgcn_s_setprio(0);

        // causal mask (scores in log2 domain; Q pre-scaled)
        if (kt + 63 > q0) {
            const int keybase = kt + 4 * hi;
#pragma unroll
            for (int r = 0; r < 16; ++r) {
                const int cr = (r & 3) + 8 * (r >> 2);
                if (keybase + cr > rowA)      sA0[r] = -3e38f;
                if (keybase + cr + 32 > rowA) sA1[r] = -3e38f;
                if (keybase + cr > rowB)      sB0[r] = -3e38f;
                if (keybase + cr + 32 > rowB) sB1[r] = -3e38f;
            }
        }

        // p = exp2(sc), lane-local sums
#pragma unroll
        for (int r = 0; r < 16; ++r) {
            float a0 = exp2f(sA0[r]), a1 = exp2f(sA1[r]);
            float b0 = exp2f(sB0[r]), b1 = exp2f(sB1[r]);
            sA0[r] = a0; sA1[r] = a1; sB0[r] = b0; sB1[r] = b1;
            lA += a0 + a1;
            lB += b0 + b1;
        }

        // P -> bf16 B-fragments (cvt_pk + permlane32_swap), per group
        s16x8 pfA[4], pfB[4];
        {
            union PW { uint32_t u[4]; s16x8 v; };
#pragma unroll
            for (int g = 0; g < 2; ++g) {
#pragma unroll
                for (int half = 0; half < 2; ++half) {
                    const f32x16& e = g ? (half ? sB1 : sB0) : (half ? sA1 : sA0);
#pragma unroll
                    for (int sl = 0; sl < 2; ++sl) {
                        const int rb = sl * 8;
                        uint32_t a0 = cvt_pk_bf16(e[rb + 0], e[rb + 1]);
                        uint32_t b0 = cvt_pk_bf16(e[rb + 4], e[rb + 5]);
                        uint32_t a1 = cvt_pk_bf16(e[rb + 2], e[rb + 3]);
                        uint32_t b1 = cvt_pk_bf16(e[rb + 6], e[rb + 7]);
                        asm("v_permlane32_swap_b32 %0, %1" : "+v"(a0), "+v"(b0));
                        asm("v_permlane32_swap_b32 %0, %1" : "+v"(a1), "+v"(b1));
                        PW pw; pw.u[0] = a0; pw.u[1] = a1; pw.u[2] = b0; pw.u[3] = b1;
                        (g ? pfB : pfA)[half * 2 + sl] = pw.v;
                    }
                }
            }
        }

        s16x8 vf[8];
#pragma unroll
        for (int db = 0; db < 2; ++db)
#pragma unroll
            for (int ks = 0; ks < 4; ++ks)
                vf[db * 4 + ks] = *reinterpret_cast<const s16x8*>(
                    &Vh[(db * 32 + ql) * 64 + (((ks * 32 + hi * 16) ^ swz) >> 1)]);

        __builtin_amdgcn_s_setprio(1);
#pragma unroll
        for (int ks = 0; ks < 4; ++ks) {
            oA0 = __builtin_amdgcn_mfma_f32_32x32x16_bf16(vf[ks],     pfA[ks], oA0, 0, 0, 0);
            oA1 = __builtin_amdgcn_mfma_f32_32x32x16_bf16(vf[4 + ks], pfA[ks], oA1, 0, 0, 0);
            oB0 = __builtin_amdgcn_mfma_f32_32x32x16_bf16(vf[ks],     pfB[ks], oB0, 0, 0, 0);
            oB1 = __builtin_amdgcn_mfma_f32_32x32x16_bf16(vf[4 + ks], pfB[ks], oB1, 0, 0, 0);
        }
        __builtin_amdgcn_s_setprio(0);
    };

    // prologue: stage tiles 0,1 into buffer 0 halves 0,1
#pragma unroll
    for (int half = 0; half < 2; ++half) {
        const int kt2 = half * 64;
#pragma unroll
        for (int i = 0; i < 2; ++i) {
            gload_lds16(kb_ + (size_t)(kt2 + w * 16 + i * 8 + srow) * DK_ + scol,
                        &Kl[0][half][w * 1024 + i * 512]);
            gload_lds16(vb_ + (size_t)(w * 16 + i * 8 + srow) * S_ + kt2 + scol,
                        &Vl[0][half][w * 1024 + i * 512]);
        }
    }

    for (int t = 0; t < ntmax; t += 2) {
        const int cur = (t >> 1) & 1;
        __syncthreads();   // staging of tiles t,t+1 landed; prev buffer reads done
        if (t + 2 < ntmax) {
            const int nb = cur ^ 1;
#pragma unroll
            for (int half = 0; half < 2; ++half) {
                const int kt2 = (t + 2 + half) * 64;
#pragma unroll
                for (int i = 0; i < 2; ++i) {
                    gload_lds16(kb_ + (size_t)(kt2 + w * 16 + i * 8 + srow) * DK_ + scol,
                                &Kl[nb][half][w * 1024 + i * 512]);
                    gload_lds16(vb_ + (size_t)(w * 16 + i * 8 + srow) * S_ + kt2 + scol,
                                &Vl[nb][half][w * 1024 + i * 512]);
                }
            }
        }
        do_tile(t * 64,       &Kl[cur][0][0], &Vl[cur][0][0]);
        do_tile((t + 1) * 64, &Kl[cur][1][0], &Vl[cur][1][0]);
    }

    __syncthreads();   // all waves done with Kl before aliased epilogue writes

    // epilogue: per group, reduce l, transpose through obuf, coalesced store
    lA += __shfl_xor(lA, 32);
    lB += __shfl_xor(lB, 32);
    const float rinvA = 1.0f / lA;
    const float rinvB = 1.0f / lB;

#pragma unroll
    for (int g = 0; g < 2; ++g) {
        const float rinv = g ? rinvB : rinvA;
#pragma unroll
        for (int db = 0; db < 2; ++db) {
            const f32x16& o = g ? (db ? oB1 : oB0) : (db ? oA1 : oA0);
#pragma unroll
            for (int rq = 0; rq < 4; ++rq) {
                uint2 val;
                val.x = cvt_pk_bf16(o[4 * rq + 0] * rinv, o[4 * rq + 1] * rinv);
                val.y = cvt_pk_bf16(o[4 * rq + 2] * rinv, o[4 * rq + 3] * rinv);
                int colb = (db * 32 + 8 * rq + 4 * hi) * 2;
                *reinterpret_cast<uint2*>(obb + ql * 128 + (colb ^ swz)) = val;
            }
        }
        uint16_t* orow = attn + ((size_t)b * S_ + q0 + g * 32 + ql) * DM_ + hh * 64 + hi * 32;
#pragma unroll
        for (int i = 0; i < 4; ++i) {
            int colb = hi * 64 + i * 16;
            s16x8 vrow = *reinterpret_cast<const s16x8*>(obb + ql * 128 + (colb ^ swz));
            *reinterpret_cast<s16x8*>(orow + i * 8) = vrow;
        }
    }
}

extern "C" void kernel_launch(void* const* d_in, const int* in_sizes, int n_in,
                              void* d_out, int out_size, void* d_ws, size_t ws_size,
                              hipStream_t stream) {
    (void)in_sizes; (void)n_in; (void)out_size;
    const float* x   = (const float*)d_in[0];
    const float* wq  = (const float*)d_in[1];
    const float* wk  = (const float*)d_in[2];
    const float* wv  = (const float*)d_in[3];
    const float* wo  = (const float*)d_in[4];
    const int* tpos  = (const int*)d_in[5];
    float* out = (float*)d_out;

    const size_t NX = (size_t)M_ * DM_;   // 8388608
    const size_t NW = (size_t)DM_ * DM_;  // 1048576
    const size_t need = (NX + 4 * NW + 4 * NX) * sizeof(uint16_t);
    if (ws_size < need) return;

    uint16_t* ws  = (uint16_t*)d_ws;
    uint16_t* xb  = ws;
    uint16_t* wqb = xb + NX;
    uint16_t* wkb = wqb + NW;
    uint16_t* wvb = wkb + NW;
    uint16_t* wob = wvb + NW;
    uint16_t* qb  = wob + NW;
    uint16_t* kb  = qb + NX;
    uint16_t* vtb = kb + NX;
    uint16_t* ab  = vtb + NX;

    cvt_all<<<(int)((NX + 4 * NW) / 1024), 256, 0, stream>>>(x, wq, wk, wv, wo,
                                                             xb, wqb, wkb, wvb, wob);

    gemm_qkv<<<dim3(24, M_ / 128), 256, 0, stream>>>(xb, wqb, wkb, wvb, qb, kb, vtb);

    int npairs_k = B_ * H_ * S_ * (DK_ / 2);   // K only; Q roped inside flash
    rope_kernel<<<npairs_k / 256, 256, 0, stream>>>(kb, tpos, npairs_k);

    flash_attn<<<dim3(512), 256, 0, stream>>>(qb, kb, vtb, tpos, ab);

    gemm_out<<<dim3(M_ / 128, DM_ / 128), 256, 0, stream>>>(ab, wob, out, M_, DM_, DM_);
}